// Round 13
// baseline (1200.638 us; speedup 1.0000x reference)
//
#include <hip/hip_runtime.h>
#include <cmath>

// ---- problem dims (fixed per reference) ----
#define YCH 8        // y_channels
#define NTR 16       // trials
#define LLEN 4096    // trial length
#define CK  16       // kernels per channel
#define KS  64       // kernel size
#define ENC 4033     // LLEN - KS + 1
#define NP  128      // YCH*NTR independent problems
#define INV_LIP 0.1f     // 1/10
#define THRESH 0.01f     // LAM/LIP = 0.1/10

#define TI  512          // x outputs per block per channel
#define BW4 160          // B f4-slots per channel: [i0-64, i0+576) = 640 floats
#define BP4 170          // padded channel pitch in f4 (SW(159)=168 < 170)
#define RW4 144          // rs f4-slots: 576 floats [i0, i0+576)
#define RP4 152          // padded (SW(143)=151)
// f4-slot swizzle: +1 pad slot per 16 -> breaks the 8-way bank conflict of
// the 16B lane stride (proven r12: 650->491us)
#define SW(s) ((s) + ((s) >> 4))

typedef float vfloat4 __attribute__((ext_vector_type(4)));

// volatile 16B LDS load: cannot be rematerialized/split/CSE'd -> exactly one
// ds_read_b128, result register-resident (proven r12)
__device__ __forceinline__ vfloat4 ldvol(const vfloat4* p) {
    return *(const volatile vfloat4*)p;
}

// component by compile-time-constant index (folds; no alloca)
#define C4(v, c) ((c) == 0 ? (v).x : (c) == 1 ? (v).y : (c) == 2 ? (v).z : (v).w)
// 20-float rolling window w0..w4, f in [0,19]  (r11-verified synthesis mapping)
#define GW5(f) ((f) < 4  ? C4(w0, (f))      : \
                (f) < 8  ? C4(w1, (f) - 4)  : \
                (f) < 12 ? C4(w2, (f) - 8)  : \
                (f) < 16 ? C4(w3, (f) - 12) : C4(w4, (f) - 16))
// 24-float rolling window u0..u5, f in [0,23]  (analysis, 8 outputs/lane)
#define GW6(f) ((f) < 4  ? C4(u0, (f))      : \
                (f) < 8  ? C4(u1, (f) - 4)  : \
                (f) < 12 ? C4(u2, (f) - 8)  : \
                (f) < 16 ? C4(u3, (f) - 12) : \
                (f) < 20 ? C4(u4, (f) - 16) : C4(u5, (f) - 20))

// B over [gi4, gi4+3], zero outside [0, ENC):  B = a + gamma*(a - p)
__device__ __forceinline__ float4 loadB4(const float* __restrict__ A,
                                         const float* __restrict__ P,
                                         float gamma, size_t coff, int gi4)
{
    if (gi4 >= 0 && gi4 + 3 < ENC) {
        float4 a = *(const float4*)(A + coff + gi4);
        float4 p = *(const float4*)(P + coff + gi4);
        return make_float4(fmaf(gamma, a.x - p.x, a.x),
                           fmaf(gamma, a.y - p.y, a.y),
                           fmaf(gamma, a.z - p.z, a.z),
                           fmaf(gamma, a.w - p.w, a.w));
    }
    float r[4];
    #pragma unroll
    for (int j = 0; j < 4; ++j) {
        int gi = gi4 + j;
        if (gi >= 0 && gi < ENC) {
            float a = A[coff + gi], p = P[coff + gi];
            r[j] = fmaf(gamma, a - p, a);
        } else r[j] = 0.f;
    }
    return make_float4(r[0], r[1], r[2], r[3]);
}

// =====================================================================
// fista_step: one FULL FISTA iteration per launch; A-state read ONCE.
//  p1: stage B=A+g(A-Ap) (16ch x 640, swizzled) + rs=y + hs; barrier
//  p2: synthesis: wave wv -> ch 4wv..4wv+3; lane l -> slots {l,l+64,l+128<16};
//      rolling w0..w4 (r11 identity); atomicAdd(-acc) into rs; barrier
//  p3: analysis: lane owns i=i0+8l..+7, 4 ch/wave; rolling u0..u5;
//      x_new = relu(B_lds + acc/LIP - thr) -> Anext
// grid (8, NP) x 256 thr; LDS ~50KB -> 3 blocks/CU.
// =====================================================================
__global__ __launch_bounds__(256) void fista_step(
    const float* __restrict__ y, const float* __restrict__ H,
    const float* __restrict__ Acur, const float* __restrict__ Aprev,
    float gamma, int first, float* __restrict__ Anext)
{
    __shared__ __align__(16) float Bs[CK * BP4 * 4];  // 43520 B
    __shared__ __align__(16) float rs[RP4 * 4];       //  2432 B
    __shared__ __align__(16) float hs[CK * KS];       //  4096 B

    const int tid = threadIdx.x;
    const int i0  = blockIdx.x * TI;
    const int p   = blockIdx.y;
    const int n = p & 15, ch = p >> 4;

    // ---- phase 1: staging ----
    ((float4*)hs)[tid] = ((const float4*)(H + (size_t)ch * CK * KS))[tid]; // 256 f4

    if (tid < RW4) {
        int gi4 = i0 + 4 * tid;
        const float* yb = y + ((size_t)n * YCH + ch) * LLEN;
        float4 v;
        if (gi4 + 3 < LLEN) v = *(const float4*)(yb + gi4);
        else {
            float r[4];
            #pragma unroll
            for (int j = 0; j < 4; ++j) r[j] = (gi4 + j < LLEN) ? yb[gi4 + j] : 0.f;
            v = make_float4(r[0], r[1], r[2], r[3]);
        }
        ((float4*)rs)[SW(tid)] = v;
    }

    const size_t pbase = (size_t)p * CK * ENC;
    if (!first) {
        // 16 ch x 160 f4 = 2560 f4 -> exactly 10 per thread
        #pragma unroll
        for (int s = 0; s < 10; ++s) {
            int f   = tid + 256 * s;
            int c   = f / BW4;
            int off = f - c * BW4;
            ((float4*)Bs)[c * BP4 + SW(off)] =
                loadB4(Acur, Aprev, gamma, pbase + (size_t)c * ENC,
                       i0 - 64 + 4 * off);
        }
    }
    __syncthreads();

    const int wv = tid >> 6, l = tid & 63;

    // ---- phase 2: synthesis conv, rs -= wave-quad partials ----
    if (!first) {
        #pragma unroll
        for (int s3 = 0; s3 < 3; ++s3) {
            const int slot = l + 64 * s3;       // output floats 4*slot..+3
            if (slot < RW4) {
                float acc[4] = {0.f, 0.f, 0.f, 0.f};
                #pragma unroll
                for (int cc = 0; cc < 4; ++cc) {
                    const int c = 4 * wv + cc;
                    const vfloat4* xb = (const vfloat4*)Bs + c * BP4;
                    const float4*  hc = (const float4*)(hs + c * KS);
                    // r11-verified identity: t=i0+4*slot+j, k=16kg+mm,
                    // window float = 16-mm+j over base slot (slot+12-4kg)
                    vfloat4 w0 = ldvol(xb + SW(slot + 12));
                    vfloat4 w1 = ldvol(xb + SW(slot + 13));
                    vfloat4 w2 = ldvol(xb + SW(slot + 14));
                    vfloat4 w3 = ldvol(xb + SW(slot + 15));
                    vfloat4 w4 = ldvol(xb + SW(slot + 16));
                    #pragma unroll
                    for (int kg = 0; kg < 4; ++kg) {
                        const float4 h0 = hc[4*kg],   h1 = hc[4*kg+1];
                        const float4 h2 = hc[4*kg+2], h3 = hc[4*kg+3];
                        #pragma unroll
                        for (int mm = 0; mm < 16; ++mm) {   // tap k=16kg+mm
                            const float4 hv = (mm < 4 ? h0 : mm < 8 ? h1 :
                                               mm < 12 ? h2 : h3);
                            const float hm = C4(hv, mm & 3);
                            #pragma unroll
                            for (int j = 0; j < 4; ++j)
                                acc[j] = fmaf(GW5(16 - mm + j), hm, acc[j]);
                        }
                        if (kg < 3) {
                            w4 = w0;
                            w0 = ldvol(xb + SW(slot + 8  - 4 * kg));
                            w1 = ldvol(xb + SW(slot + 9  - 4 * kg));
                            w2 = ldvol(xb + SW(slot + 10 - 4 * kg));
                            w3 = ldvol(xb + SW(slot + 11 - 4 * kg));
                        }
                    }
                }
                float* rf = rs + 4 * SW(slot);
                #pragma unroll
                for (int j = 0; j < 4; ++j) atomicAdd(&rf[j], -acc[j]);
            }
        }
        __syncthreads();
    }

    // ---- phase 3: analysis conv + update ----
    const int i = i0 + 8 * l;
    const vfloat4* rv = (const vfloat4*)rs;
    #pragma unroll
    for (int cc = 0; cc < 4; ++cc) {
        const int c = 4 * wv + cc;
        const float4* hc = (const float4*)(hs + c * KS);
        float acc[8] = {0.f,0.f,0.f,0.f,0.f,0.f,0.f,0.f};
        // window: rs floats [8l, 8l+71] -> slots 2l..2l+17; per kg 6 slots,
        // w-float = mm + j (k=16kg+mm, base slot 2l+4kg)
        vfloat4 u0 = ldvol(rv + SW(2*l + 0));
        vfloat4 u1 = ldvol(rv + SW(2*l + 1));
        vfloat4 u2 = ldvol(rv + SW(2*l + 2));
        vfloat4 u3 = ldvol(rv + SW(2*l + 3));
        vfloat4 u4 = ldvol(rv + SW(2*l + 4));
        vfloat4 u5 = ldvol(rv + SW(2*l + 5));
        #pragma unroll
        for (int kg = 0; kg < 4; ++kg) {
            const float4 h0 = hc[4*kg],   h1 = hc[4*kg+1];
            const float4 h2 = hc[4*kg+2], h3 = hc[4*kg+3];
            #pragma unroll
            for (int mm = 0; mm < 16; ++mm) {       // tap k = 16kg+mm
                const float4 hv = (mm < 4 ? h0 : mm < 8 ? h1 :
                                   mm < 12 ? h2 : h3);
                const float hm = C4(hv, mm & 3);
                #pragma unroll
                for (int j = 0; j < 8; ++j)
                    acc[j] = fmaf(GW6(mm + j), hm, acc[j]);
            }
            if (kg < 3) {
                u0 = u4; u1 = u5;
                u2 = ldvol(rv + SW(2*l + 4*kg + 6));
                u3 = ldvol(rv + SW(2*l + 4*kg + 7));
                u4 = ldvol(rv + SW(2*l + 4*kg + 8));
                u5 = ldvol(rv + SW(2*l + 4*kg + 9));
            }
        }

        // B-term from the staged LDS slab: B[c, i+j] = float 64+8l+j
        vfloat4 b0, b1;
        if (!first) {
            const vfloat4* xb = (const vfloat4*)Bs + c * BP4;
            b0 = ldvol(xb + SW(16 + 2*l));
            b1 = ldvol(xb + SW(17 + 2*l));
        }
        const size_t idx = pbase + (size_t)c * ENC + i;
        if (i + 7 < ENC) {
            float o[8];
            #pragma unroll
            for (int j = 0; j < 8; ++j) {
                const float Bv = first ? 0.f
                                       : (j < 4 ? C4(b0, j) : C4(b1, j - 4));
                o[j] = fmaxf(fmaf(acc[j], INV_LIP, Bv) - THRESH, 0.f);
            }
            *(float4*)(Anext + idx)     = make_float4(o[0], o[1], o[2], o[3]);
            *(float4*)(Anext + idx + 4) = make_float4(o[4], o[5], o[6], o[7]);
        } else {
            #pragma unroll
            for (int j = 0; j < 8; ++j) {
                if (i + j < ENC) {
                    const float Bv = first ? 0.f
                                           : (j < 4 ? C4(b0, j) : C4(b1, j - 4));
                    Anext[idx + j] = fmaxf(fmaf(acc[j], INV_LIP, Bv) - THRESH, 0.f);
                }
            }
        }
    }
}

// =====================================================================
extern "C" void kernel_launch(void* const* d_in, const int* in_sizes, int n_in,
                              void* d_out, int out_size, void* d_ws, size_t ws_size,
                              hipStream_t stream)
{
    const float* y = (const float*)d_in[0];   // [NTR, YCH, LLEN]
    const float* H = (const float*)d_in[1];   // [YCH, CK, 1, KS]

    float* bufA = (float*)d_ws;               // A_t for even t
    float* bufB = (float*)d_out;              // A_t for odd t (A9 -> d_out)

    double s[11]; s[0] = 1.0;
    for (int t = 1; t <= 10; ++t) s[t] = 0.5 * (1.0 + sqrt(1.0 + 4.0 * s[t-1] * s[t-1]));

    dim3 grid(8, NP);

    for (int t = 0; t < 10; ++t) {
        float gamma = (t == 0) ? 0.f : (float)((s[t-1] - 1.0) / s[t]);
        float* Anext       = (t & 1) ? bufB : bufA;
        const float* Acur  = (t & 1) ? bufA : bufB;              // A_{t-1}
        const float* Aprev = (t <= 1) ? Acur                     // gamma==0, unused
                                      : ((t & 1) ? bufB : bufA); // A_{t-2}
        fista_step<<<grid, 256, 0, stream>>>(y, H, Acur, Aprev, gamma,
                                             (t == 0) ? 1 : 0, Anext);
    }
}

// Round 14
// 482.081 us; speedup vs baseline: 2.4905x; 2.4905x over previous
//
#include <hip/hip_runtime.h>
#include <cmath>

// ---- problem dims (fixed per reference) ----
#define YCH 8        // y_channels
#define NTR 16       // trials
#define LLEN 4096    // trial length
#define CK  16       // kernels per channel
#define KS  64       // kernel size
#define ENC 4033     // LLEN - KS + 1
#define NP  128      // YCH*NTR independent problems
#define INV_LIP 0.1f     // 1/10
#define THRESH 0.01f     // LAM/LIP = 0.1/10

#define XW4 272          // float4 slots per 1088-float channel window
#define XP4 289          // padded slots per channel (SW(271)=287 < 289)
// f4-slot swizzle: +1 pad slot per 16 -> breaks the 8-way bank conflict of
// the 16B lane stride (proven r12: 650->491us)
#define SW(s) ((s) + ((s) >> 4))

typedef float vfloat4 __attribute__((ext_vector_type(4)));

// volatile 16B LDS load: cannot be rematerialized/split/CSE'd -> exactly one
// ds_read_b128, result register-resident (proven r12)
__device__ __forceinline__ vfloat4 ldvol(const vfloat4* p) {
    return *(const volatile vfloat4*)p;
}

// component by compile-time-constant index (folds; no alloca)
#define C4(v, c) ((c) == 0 ? (v).x : (c) == 1 ? (v).y : (c) == 2 ? (v).z : (v).w)
// 20-float rolling window w0..w4, f in [0,19]  (r11/r12-verified mapping)
#define GW5(f) ((f) < 4  ? C4(w0, (f))      : \
                (f) < 8  ? C4(w1, (f) - 4)  : \
                (f) < 12 ? C4(w2, (f) - 8)  : \
                (f) < 16 ? C4(w3, (f) - 12) : C4(w4, (f) - 16))

// plain A load over [gi4, gi4+3], zero outside [0, ENC)
__device__ __forceinline__ float4 loadA4(const float* __restrict__ A,
                                         size_t coff, int gi4)
{
    if (gi4 >= 0 && gi4 + 3 < ENC) return *(const float4*)(A + coff + gi4);
    float r[4];
    #pragma unroll
    for (int j = 0; j < 4; ++j) {
        int gi = gi4 + j;
        r[j] = (gi >= 0 && gi < ENC) ? A[coff + gi] : 0.f;
    }
    return make_float4(r[0], r[1], r[2], r[3]);
}

// =====================================================================
// synth_half: S[h][p][t] = sum_{c in half h, k} A[p,c,t-k]*H[ch,c,k]
// Linearity trick: synthesize A (NOT the momentum-extrapolated B), so only
// ONE A-stream is read; fista recombines res = y-(1+g)S_cur+g*S_prev.
// block = (ttile=1024, half, p) -> grid (4,2,128) x 256 thr, 4 out/thread.
// Inner loop: proven r12 recipe (swizzled LDS + volatile b128 rolling win).
//   identity (r11-verified): t=t0+4*tid+j, k=16kg+mm, window float 16-mm+j
//   over base slot (tid+12-4kg).
// =====================================================================
__global__ __launch_bounds__(256) void synth_half(
    const float* __restrict__ H, const float* __restrict__ A,
    float* __restrict__ S)
{
    __shared__ __align__(16) float xs[8 * XP4 * 4];  // 36992 B (swizzled)
    __shared__ __align__(16) float hs[8 * KS];       //  2048 B
    const int tid = threadIdx.x;
    const int t0  = blockIdx.x * 1024;
    const int c0  = blockIdx.y * 8;
    const int p   = blockIdx.z;
    const int ch  = p >> 4;

    if (tid < 128)
        ((float4*)hs)[tid] = ((const float4*)(H + ((size_t)ch * CK + c0) * KS))[tid];

    const size_t pbase = (size_t)p * CK * ENC;
    // stage 8 channels x 272 f4 = 2176 f4 (8.5 per thread), swizzled slots
    #pragma unroll
    for (int s = 0; s < 9; ++s) {
        int l4 = tid + 256 * s;
        if (l4 < 8 * XW4) {
            int c   = l4 / XW4;
            int off = l4 - c * XW4;
            ((float4*)xs)[c * XP4 + SW(off)] =
                loadA4(A, pbase + (size_t)(c0 + c) * ENC, t0 - 64 + 4 * off);
        }
    }
    __syncthreads();

    float acc[4] = {0.f, 0.f, 0.f, 0.f};

    #pragma unroll
    for (int cc = 0; cc < 8; ++cc) {
        const vfloat4* xb = (const vfloat4*)xs + cc * XP4;
        const float4*  hc = (const float4*)(hs + cc * KS);

        vfloat4 w0 = ldvol(xb + SW(tid + 12));
        vfloat4 w1 = ldvol(xb + SW(tid + 13));
        vfloat4 w2 = ldvol(xb + SW(tid + 14));
        vfloat4 w3 = ldvol(xb + SW(tid + 15));
        vfloat4 w4 = ldvol(xb + SW(tid + 16));
        #pragma unroll
        for (int kg = 0; kg < 4; ++kg) {
            const float4 h0 = hc[4*kg],   h1 = hc[4*kg+1];
            const float4 h2 = hc[4*kg+2], h3 = hc[4*kg+3];
            #pragma unroll
            for (int mm = 0; mm < 16; ++mm) {       // tap k = 16kg+mm
                const float4 hv = (mm < 4 ? h0 : mm < 8 ? h1 : mm < 12 ? h2 : h3);
                const float hm = C4(hv, mm & 3);
                #pragma unroll
                for (int j = 0; j < 4; ++j)
                    acc[j] = fmaf(GW5(16 - mm + j), hm, acc[j]);
            }
            if (kg < 3) {
                w4 = w0;
                w0 = ldvol(xb + SW(tid + 8  - 4 * kg));
                w1 = ldvol(xb + SW(tid + 9  - 4 * kg));
                w2 = ldvol(xb + SW(tid + 10 - 4 * kg));
                w3 = ldvol(xb + SW(tid + 11 - 4 * kg));
            }
        }
    }

    const int t = t0 + 4 * tid;
    *(float4*)(S + ((size_t)blockIdx.y * NP + p) * LLEN + t) =
        make_float4(acc[0], acc[1], acc[2], acc[3]);
}

// =====================================================================
// fista_quad (r12 body; staging now recombines S generations):
//   rs = y - c1*(Sc0+Sc1) + c2*(Sp0+Sp1),  c1 = 1+gamma, c2 = gamma
//   g[c,i] = sum_k rs[i+k]*H[ch,c,k];  x_new = relu(B + g/LIP - thr)
// =====================================================================
__global__ __launch_bounds__(256) void fista_quad(
    const float* __restrict__ y,
    const float* __restrict__ Scur, const float* __restrict__ Sprev,
    const float* __restrict__ H,
    const float* __restrict__ Acur, const float* __restrict__ Aprev,
    float gamma, int first, int two, float c1, float c2,
    float* __restrict__ Anext)
{
    __shared__ __align__(16) float rs[XW4 * 4];
    __shared__ __align__(16) float hs[4 * KS];
    const int tid = threadIdx.x;
    const int i0  = blockIdx.x * 1024;
    const int c0  = blockIdx.y * 4;
    const int p   = blockIdx.z;
    const int n = p & 15, ch = p >> 4;

    if (tid < 64)
        ((float4*)hs)[tid] = ((const float4*)(H + ((size_t)ch * CK + c0) * KS))[tid];

    const float* ybase = y + ((size_t)n * YCH + ch) * LLEN;
    #pragma unroll
    for (int s = 0; s < 2; ++s) {
        int l4 = tid + 256 * s;
        if (l4 < XW4) {
            int gi4 = i0 + 4 * l4;
            float4 v;
            if (gi4 + 3 < LLEN) {
                v = *(const float4*)(ybase + gi4);
                if (!first) {
                    float4 a = *(const float4*)(Scur + ((size_t)0 * NP + p) * LLEN + gi4);
                    float4 b = *(const float4*)(Scur + ((size_t)1 * NP + p) * LLEN + gi4);
                    v.x -= c1 * (a.x + b.x); v.y -= c1 * (a.y + b.y);
                    v.z -= c1 * (a.z + b.z); v.w -= c1 * (a.w + b.w);
                    if (two) {
                        float4 e = *(const float4*)(Sprev + ((size_t)0 * NP + p) * LLEN + gi4);
                        float4 f = *(const float4*)(Sprev + ((size_t)1 * NP + p) * LLEN + gi4);
                        v.x += c2 * (e.x + f.x); v.y += c2 * (e.y + f.y);
                        v.z += c2 * (e.z + f.z); v.w += c2 * (e.w + f.w);
                    }
                }
            } else {
                float r[4];
                #pragma unroll
                for (int j = 0; j < 4; ++j) {
                    int gi = gi4 + j;
                    if (gi < LLEN) {
                        float t = ybase[gi];
                        if (!first) {
                            t -= c1 * (Scur[((size_t)0 * NP + p) * LLEN + gi] +
                                       Scur[((size_t)1 * NP + p) * LLEN + gi]);
                            if (two)
                                t += c2 * (Sprev[((size_t)0 * NP + p) * LLEN + gi] +
                                           Sprev[((size_t)1 * NP + p) * LLEN + gi]);
                        }
                        r[j] = t;
                    } else r[j] = 0.f;
                }
                v = make_float4(r[0], r[1], r[2], r[3]);
            }
            ((float4*)rs)[l4] = v;
        }
    }
    __syncthreads();

    // hoisted register window rs[4*tid .. 4*tid+67], shared by 4 channels
    float wf[68];
    const float4* rr = (const float4*)rs + tid;
    #pragma unroll
    for (int q = 0; q < 17; ++q) {
        float4 t4 = rr[q];
        wf[4*q] = t4.x; wf[4*q+1] = t4.y; wf[4*q+2] = t4.z; wf[4*q+3] = t4.w;
    }

    const int i = i0 + 4 * tid;
    const size_t pb = (size_t)p * CK * ENC;
    const bool vec = (i + 3 < ENC);

    float4 a0 = make_float4(0,0,0,0), p0 = make_float4(0,0,0,0);
    if (!first && vec) {
        a0 = *(const float4*)(Acur  + pb + (size_t)c0 * ENC + i);
        p0 = *(const float4*)(Aprev + pb + (size_t)c0 * ENC + i);
    }

    for (int cc = 0; cc < 4; ++cc) {
        float4 a1 = make_float4(0,0,0,0), p1 = make_float4(0,0,0,0);
        if (!first && vec && cc < 3) {
            a1 = *(const float4*)(Acur  + pb + (size_t)(c0 + cc + 1) * ENC + i);
            p1 = *(const float4*)(Aprev + pb + (size_t)(c0 + cc + 1) * ENC + i);
        }

        float acc[4] = {0.f, 0.f, 0.f, 0.f};
        const float4* hc = (const float4*)(hs + cc * KS);
        #pragma unroll
        for (int g = 0; g < 16; ++g) {
            float4 h4 = hc[g];
            float hh[4] = {h4.x, h4.y, h4.z, h4.w};
            #pragma unroll
            for (int m = 0; m < 4; ++m) {
                const int k = 4 * g + m;
                #pragma unroll
                for (int j = 0; j < 4; ++j)
                    acc[j] = fmaf(wf[k + j], hh[m], acc[j]);
            }
        }

        const size_t idx = pb + (size_t)(c0 + cc) * ENC + i;
        if (vec) {
            float B[4] = {0.f, 0.f, 0.f, 0.f};
            if (!first) {
                float av[4] = {a0.x, a0.y, a0.z, a0.w};
                float pv[4] = {p0.x, p0.y, p0.z, p0.w};
                #pragma unroll
                for (int j = 0; j < 4; ++j) B[j] = fmaf(gamma, av[j] - pv[j], av[j]);
            }
            float4 o;
            o.x = fmaxf(fmaf(acc[0], INV_LIP, B[0]) - THRESH, 0.f);
            o.y = fmaxf(fmaf(acc[1], INV_LIP, B[1]) - THRESH, 0.f);
            o.z = fmaxf(fmaf(acc[2], INV_LIP, B[2]) - THRESH, 0.f);
            o.w = fmaxf(fmaf(acc[3], INV_LIP, B[3]) - THRESH, 0.f);
            *(float4*)(Anext + idx) = o;
        } else if (i < ENC) {
            #pragma unroll
            for (int j = 0; j < 4; ++j) {
                if (i + j < ENC) {
                    float B = 0.f;
                    if (!first) {
                        float a = Acur[idx + j], pp = Aprev[idx + j];
                        B = fmaf(gamma, a - pp, a);
                    }
                    Anext[idx + j] = fmaxf(fmaf(acc[j], INV_LIP, B) - THRESH, 0.f);
                }
            }
        }
        a0 = a1; p0 = p1;
    }
}

// =====================================================================
extern "C" void kernel_launch(void* const* d_in, const int* in_sizes, int n_in,
                              void* d_out, int out_size, void* d_ws, size_t ws_size,
                              hipStream_t stream)
{
    const float* y = (const float*)d_in[0];   // [NTR, YCH, LLEN]
    const float* H = (const float*)d_in[1];   // [YCH, CK, 1, KS]
    const size_t XSZ = (size_t)NP * CK * ENC; // 8,259,584 floats
    const size_t RSZ = (size_t)NP * LLEN;     //   524,288 floats

    float* bufA = (float*)d_ws;               // A_t for even t
    float* bufB = (float*)d_out;              // A_t for odd t (A9 -> d_out)
    float* Sgen = bufA + XSZ;                 // 2 gens x [2][NP][LLEN] = 4*RSZ

    double s[11]; s[0] = 1.0;
    for (int t = 1; t <= 10; ++t) s[t] = 0.5 * (1.0 + sqrt(1.0 + 4.0 * s[t-1] * s[t-1]));

    dim3 gS(4, 2, NP), gF(4, 4, NP);

    for (int t = 0; t < 10; ++t) {
        float gamma = (t == 0) ? 0.f : (float)((s[t-1] - 1.0) / s[t]);
        float* Anext       = (t & 1) ? bufB : bufA;
        const float* Acur  = (t & 1) ? bufA : bufB;              // A_{t-1}
        const float* Aprev = (t <= 1) ? Acur                     // gamma==0, unused
                                      : ((t & 1) ? bufB : bufA); // A_{t-2}
        if (t == 0) {
            // B_0 = 0 => rs = y; fuse into update kernel (first=1)
            fista_quad<<<gF, 256, 0, stream>>>(y, Sgen, Sgen, H, bufA, bufA,
                                               0.f, 1, 0, 0.f, 0.f, bufA);
        } else {
            float* Sc = Sgen + (size_t)((t - 1) & 1) * 2 * RSZ;  // S_{t-1}
            float* Sp = Sgen + (size_t)(t & 1) * 2 * RSZ;        // S_{t-2} (t>=2)
            synth_half<<<gS, 256, 0, stream>>>(H, Acur, Sc);
            fista_quad<<<gF, 256, 0, stream>>>(y, Sc, Sp, H, Acur, Aprev,
                                               gamma, 0, (t >= 2) ? 1 : 0,
                                               1.f + gamma, gamma, Anext);
        }
    }
}